// Round 12
// baseline (780.055 us; speedup 1.0000x reference)
//
#include <hip/hip_runtime.h>
#include <math.h>

#define NROWS  16384   // B*S
#define DMODEL 1024
#define NHEAD  16
#define HDIM   64
#define SEQ    4096
#define NBATCH 4
#define NBH    64      // NBATCH*NHEAD
#define SCHUNK 16      // split-K chunks over S for kv aggregation
#define M1     1048576u

typedef __attribute__((ext_vector_type(8)))  short bf16x8;
typedef __attribute__((ext_vector_type(4)))  float f32x4;
typedef __attribute__((ext_vector_type(16))) float f32x16;

#define VMCNT(N) asm volatile("s_waitcnt vmcnt(" #N ")" ::: "memory")
#define LGKM0()  asm volatile("s_waitcnt lgkmcnt(0)" ::: "memory")

__device__ __forceinline__ unsigned short f2bf(float f) {
    unsigned u = __float_as_uint(f);
    u += 0x7FFFu + ((u >> 16) & 1u);   // round-to-nearest-even
    return (unsigned short)(u >> 16);
}
__device__ __forceinline__ float bf2f(unsigned short h) {
    return __uint_as_float((unsigned)h << 16);
}

__device__ __forceinline__ void gload16(const void* g, void* l) {
    __builtin_amdgcn_global_load_lds(
        (const __attribute__((address_space(1))) unsigned int*)g,
        (__attribute__((address_space(3))) unsigned int*)l, 16, 0, 0);
}

// ---------------------------------------------------------------------------
// split fp32 -> bf16 hi/lo pair (grid-stride, float4/ushort4 vectorized)
// ---------------------------------------------------------------------------
__global__ __launch_bounds__(256)
void split_pair(const float* __restrict__ a, unsigned short* __restrict__ hi,
                unsigned short* __restrict__ lo, int n4)
{
    int i = blockIdx.x * 256 + threadIdx.x;
    const int stride = gridDim.x * 256;
    for (; i < n4; i += stride) {
        const float4 v = ((const float4*)a)[i];
        ushort4 H, L;
        H.x = f2bf(v.x); L.x = f2bf(v.x - bf2f(H.x));
        H.y = f2bf(v.y); L.y = f2bf(v.y - bf2f(H.y));
        H.z = f2bf(v.z); L.z = f2bf(v.z - bf2f(H.z));
        H.w = f2bf(v.w); L.w = f2bf(v.w - bf2f(H.w));
        ((ushort4*)hi)[i] = H;
        ((ushort4*)lo)[i] = L;
    }
}

// 4 weight matrices -> hi block [4096][1024] rows [k|v|q|o], lo block same
__global__ __launch_bounds__(256)
void split_w4(const float* __restrict__ a0, const float* __restrict__ a1,
              const float* __restrict__ a2, const float* __restrict__ a3,
              unsigned short* __restrict__ hib, unsigned short* __restrict__ lob)
{
    const int y = blockIdx.y;   // 0=k 1=v 2=q 3=o
    const float* src = (y == 0) ? a0 : (y == 1) ? a1 : (y == 2) ? a2 : a3;
    const int i = blockIdx.x * 256 + threadIdx.x;   // 0..262143 (= 1M/4)
    const float4 v = ((const float4*)src)[i];
    ushort4 H, L;
    H.x = f2bf(v.x); L.x = f2bf(v.x - bf2f(H.x));
    H.y = f2bf(v.y); L.y = f2bf(v.y - bf2f(H.y));
    H.z = f2bf(v.z); L.z = f2bf(v.z - bf2f(H.z));
    H.w = f2bf(v.w); L.w = f2bf(v.w - bf2f(H.w));
    const size_t o = (size_t)y * M1 + (size_t)i * 4;
    *(ushort4*)&hib[o] = H;
    *(ushort4*)&lob[o] = L;
}

// ---------------------------------------------------------------------------
// Split-bf16 GEMM (NT), BARRIER-FREE per-wave private pipeline.
// Each wave = one independent 64x64 output job. Private 16KB LDS region
// (8 waves x 16KB = 128KB), 4 planes [Ah|Al|Wh|Wl] of 64 rows x 32 k bf16.
// Per BK=32 tile: vmcnt(0) own loads -> 16 ds_read_b128 to regs ->
// lgkmcnt(0)+sched_barrier (overwrite fence) -> issue 16 gload16 (kt+1) ->
// 24 x mfma_32x32x16 (3 passes hh+hl+lh, 2 k-halves). NO s_barrier anywhere:
// vmcnt/lgkmcnt are per-wave. 2 waves/SIMD mutually hide stalls.
// LDS plane layout PHYS(row,kbu) = row*32 + (kbu ^ ((row&3)<<3)) (ushorts);
// staged via per-lane-permuted global source (dest stays lane-linear per
// gload_lds rule); frag reads <=2-way bank-aliased. A-reuse via L2: block's
// 8 waves share jm (A staged 8x from L2); XCD swizzle groups same-jm blocks.
// Frag semantics (A/B k-map, C/D map) identical to r11's verified gemm32.
// MODE: 0 plain, 1 elu+1, 2 fused k|v over W rows [k|v] (jn<16: k, else v).
// ---------------------------------------------------------------------------
template<int MODE>
__global__ __launch_bounds__(512)
void gemm_pw(const unsigned short* __restrict__ Ah, const unsigned short* __restrict__ Al,
             const unsigned short* __restrict__ Wh, const unsigned short* __restrict__ Wl,
             const float* __restrict__ bias0, const float* __restrict__ bias1,
             float* __restrict__ C0, float* __restrict__ C1)
{
    __shared__ unsigned short lds[65536];   // 8 x 8192 ushorts (16KB/wave)
    const int t   = threadIdx.x;
    const int l   = t & 63;
    const int wv  = t >> 6;
    const int l31 = l & 31;
    const int hi5 = l >> 5;

    int jm, jn;
    {
        const int bid = blockIdx.x;
        if (MODE == 2) { const int swz = (bid & 7) * 128 + (bid >> 3);   // 1024 blocks
                         jm = swz >> 2; jn = (swz & 3) * 8 + wv; }       // jn 0..31
        else           { const int swz = (bid & 7) * 64 + (bid >> 3);    // 512 blocks
                         jm = swz >> 1; jn = (swz & 1) * 8 + wv; }       // jn 0..15
    }
    const int arow0 = jm * 64;
    const int brow0 = jn * 64;
    const unsigned wbu = (unsigned)wv * 8192u;   // wave LDS region (ushort units)

    // stage one plane (4 gload16): dest lane-linear; source permuted so that
    // LDS holds PHYS(row,kbu) = row*32 + (kbu ^ ((row&3)<<3))
    auto stage_plane = [&](const unsigned short* gs, int rb, unsigned po, int k0u) {
#pragma unroll
        for (int g = 0; g < 4; ++g) {
            const int row  = g * 16 + (l >> 2);
            const int srcu = ((l & 3) ^ (row & 3)) << 3;
            gload16(gs + (size_t)(rb + row) * 1024 + k0u + srcu,
                    (unsigned short*)&lds[wbu + po + (unsigned)(g * 512 + l * 8)]);
        }
    };
    auto stage_tile = [&](int kt) {
        const int k0u = kt * 32;
        stage_plane(Ah, arow0, 0u,    k0u);
        stage_plane(Al, arow0, 2048u, k0u);
        stage_plane(Wh, brow0, 4096u, k0u);
        stage_plane(Wl, brow0, 6144u, k0u);
    };

    f32x16 acc[2][2];
#pragma unroll
    for (int i = 0; i < 2; ++i)
#pragma unroll
        for (int j = 0; j < 2; ++j)
#pragma unroll
            for (int e = 0; e < 16; ++e) acc[i][j][e] = 0.f;

    stage_tile(0);   // prologue: 16 loads in flight

    for (int kt = 0; kt < 32; ++kt) {
        VMCNT(0);                              // own tile-kt loads landed (per-wave)
        __builtin_amdgcn_sched_barrier(0);
        // 16 frag reads -> regs   [kh][blk][hl]
        bf16x8 af[2][2][2], bf[2][2][2];
#pragma unroll
        for (int kh = 0; kh < 2; ++kh)
#pragma unroll
            for (int blk = 0; blk < 2; ++blk) {
                const unsigned row = (unsigned)(blk * 32 + l31);
                const unsigned ko  = (unsigned)((kh * 16 + hi5 * 8) ^ ((l31 & 3) << 3));
                af[kh][blk][0] = *(const bf16x8*)&lds[wbu + 0u    + row * 32u + ko];
                af[kh][blk][1] = *(const bf16x8*)&lds[wbu + 2048u + row * 32u + ko];
                bf[kh][blk][0] = *(const bf16x8*)&lds[wbu + 4096u + row * 32u + ko];
                bf[kh][blk][1] = *(const bf16x8*)&lds[wbu + 6144u + row * 32u + ko];
            }
        LGKM0();                               // reads complete before overwrite
        __builtin_amdgcn_sched_barrier(0);
        if (kt < 31) stage_tile(kt + 1);       // issue next tile (flies under MFMA)
        __builtin_amdgcn_s_setprio(1);
#pragma unroll
        for (int kh = 0; kh < 2; ++kh)
#pragma unroll
            for (int mi = 0; mi < 2; ++mi)
#pragma unroll
                for (int ni = 0; ni < 2; ++ni) {
                    acc[mi][ni] = __builtin_amdgcn_mfma_f32_32x32x16_bf16(af[kh][mi][0], bf[kh][ni][0], acc[mi][ni], 0, 0, 0);
                    acc[mi][ni] = __builtin_amdgcn_mfma_f32_32x32x16_bf16(af[kh][mi][0], bf[kh][ni][1], acc[mi][ni], 0, 0, 0);
                    acc[mi][ni] = __builtin_amdgcn_mfma_f32_32x32x16_bf16(af[kh][mi][1], bf[kh][ni][0], acc[mi][ni], 0, 0, 0);
                }
        __builtin_amdgcn_s_setprio(0);
    }

    // epilogue: C/D layout col=lane&31, row=(reg&3)+8*(reg>>2)+4*(lane>>5) (r11-verified)
    bool elu = (MODE == 1);
    float* Cm = C0;
    const float* bm = bias0;
    int colb = brow0;
    if (MODE == 2) {
        if (jn < 16) { elu = true; }
        else         { Cm = C1; bm = bias1; colb = brow0 - 1024; }
    }
    const int r0 = arow0 + 4 * hi5;
#pragma unroll
    for (int ni = 0; ni < 2; ++ni) {
        const int col = colb + ni * 32 + l31;
        const float bv = bm[col];
#pragma unroll
        for (int mi = 0; mi < 2; ++mi) {
#pragma unroll
            for (int r = 0; r < 16; ++r) {
                const int row = r0 + mi * 32 + (r & 3) + 8 * (r >> 2);
                float v = acc[mi][ni][r] + bv;
                if (elu) v = (v > 0.f) ? (v + 1.f) : __expf(v);  // elu(v)+1
                Cm[(size_t)row * DMODEL + col] = v;
            }
        }
    }
}

// ---------------------------------------------------------------------------
// kv partials: for (b,h,sc): kvp[d][e] = sum_{s in chunk} k[s,d]*v[s,e],
// ksp[d] = sum k[s,d]. Deterministic split-K, no atomics.
// ---------------------------------------------------------------------------
__global__ __launch_bounds__(512)
void kv_partial(const float* __restrict__ k, const float* __restrict__ v,
                float* __restrict__ kvp, float* __restrict__ ksp)
{
    __shared__ float Ks[32][64];
    __shared__ float Vs[32][64];
    const int t  = threadIdx.x;
    const int bh = blockIdx.x;
    const int b  = bh >> 4;
    const int h  = bh & 15;
    const int sc = blockIdx.y;
    const int d  = t & 63;
    const int e0 = (t >> 6) * 8;

    float acc[8];
#pragma unroll
    for (int j = 0; j < 8; ++j) acc[j] = 0.f;
    float ks = 0.f;

    const size_t rowbase = (size_t)b * SEQ;
    const int sbeg = sc * (SEQ / SCHUNK);       // 256 rows per chunk
    const int send = sbeg + (SEQ / SCHUNK);
    const int lrow = t >> 4;                    // staging: 0..31
    const int lc4  = (t & 15) * 4;

    for (int s0 = sbeg; s0 < send; s0 += 32) {
        const size_t g = (rowbase + s0 + lrow) * DMODEL + h * HDIM + lc4;
        *(float4*)&Ks[lrow][lc4] = *(const float4*)&k[g];
        *(float4*)&Vs[lrow][lc4] = *(const float4*)&v[g];
        __syncthreads();
#pragma unroll 8
        for (int sp = 0; sp < 32; ++sp) {
            const float kd = Ks[sp][d];
            if (t < 64) ks += Ks[sp][t];        // wave 0 only (wave-uniform branch)
            const float4 v0 = *(const float4*)&Vs[sp][e0 + 0];
            const float4 v1 = *(const float4*)&Vs[sp][e0 + 4];
            acc[0] = fmaf(kd, v0.x, acc[0]);  acc[1] = fmaf(kd, v0.y, acc[1]);
            acc[2] = fmaf(kd, v0.z, acc[2]);  acc[3] = fmaf(kd, v0.w, acc[3]);
            acc[4] = fmaf(kd, v1.x, acc[4]);  acc[5] = fmaf(kd, v1.y, acc[5]);
            acc[6] = fmaf(kd, v1.z, acc[6]);  acc[7] = fmaf(kd, v1.w, acc[7]);
        }
        __syncthreads();
    }

    const size_t base = ((size_t)sc * NBH + bh) * HDIM;
    float4 o0; o0.x = acc[0]; o0.y = acc[1]; o0.z = acc[2]; o0.w = acc[3];
    float4 o1; o1.x = acc[4]; o1.y = acc[5]; o1.z = acc[6]; o1.w = acc[7];
    *(float4*)&kvp[(base + d) * HDIM + e0 + 0] = o0;
    *(float4*)&kvp[(base + d) * HDIM + e0 + 4] = o1;
    if (t < 64) ksp[base + t] = ks;
}

__global__ __launch_bounds__(256)
void kv_reduce(const float* __restrict__ kvp, const float* __restrict__ ksp,
               float* __restrict__ kv, float* __restrict__ ksum)
{
    const int i = blockIdx.x * 256 + threadIdx.x;
    const int NKV = NBH * HDIM * HDIM;
    if (i < NKV) {
        float s = 0.f;
#pragma unroll
        for (int c = 0; c < SCHUNK; ++c) s += kvp[(size_t)c * NKV + i];
        kv[i] = s;
    }
    if (i < NBH * HDIM) {
        float s = 0.f;
#pragma unroll
        for (int c = 0; c < SCHUNK; ++c) s += ksp[(size_t)c * NBH * HDIM + i];
        ksum[i] = s;
    }
}

// ---------------------------------------------------------------------------
// att[s,e] = (sum_d q[s,d]*kv[d,e]) / (sum_d q[s,d]*ksum[d] + 1e-6),
// written directly as bf16 hi/lo (fused split for the final GEMM's A-operand).
// ---------------------------------------------------------------------------
__global__ __launch_bounds__(256)
void qkv_norm(const float* __restrict__ q, const float* __restrict__ kv,
              const float* __restrict__ ksum,
              unsigned short* __restrict__ ah, unsigned short* __restrict__ al)
{
    __shared__ float Qs[64][68];
    __shared__ float KVs[64][64];
    __shared__ float kss[64];
    const int t  = threadIdx.x;
    const int s0 = blockIdx.x * 64;
    const int b  = blockIdx.y;
    const int h  = blockIdx.z;
    const int bh = b * NHEAD + h;

#pragma unroll
    for (int i = 0; i < 4; ++i) {
        const int idx = i * 256 + t;
        const int row = idx >> 4;
        const int c4  = (idx & 15) * 4;
        const float4 vq = *(const float4*)&q[((size_t)b * SEQ + s0 + row) * DMODEL + h * HDIM + c4];
        *(float4*)&Qs[row][c4] = vq;
        *(float4*)&((float*)KVs)[idx * 4] = *(const float4*)&kv[(size_t)bh * HDIM * HDIM + idx * 4];
    }
    if (t < 64) kss[t] = ksum[(size_t)bh * HDIM + t];
    __syncthreads();

    const int r  = t >> 2;
    const int e0 = (t & 3) * 16;
    float out[16];
#pragma unroll
    for (int j = 0; j < 16; ++j) out[j] = 0.f;
    float nrm = 0.f;

#pragma unroll 8
    for (int d = 0; d < 64; ++d) {
        const float qd = Qs[r][d];
        nrm = fmaf(qd, kss[d], nrm);
        const float4 k0 = *(const float4*)&KVs[d][e0 + 0];
        const float4 k1 = *(const float4*)&KVs[d][e0 + 4];
        const float4 k2 = *(const float4*)&KVs[d][e0 + 8];
        const float4 k3 = *(const float4*)&KVs[d][e0 + 12];
        out[0]  = fmaf(qd, k0.x, out[0]);  out[1]  = fmaf(qd, k0.y, out[1]);
        out[2]  = fmaf(qd, k0.z, out[2]);  out[3]  = fmaf(qd, k0.w, out[3]);
        out[4]  = fmaf(qd, k1.x, out[4]);  out[5]  = fmaf(qd, k1.y, out[5]);
        out[6]  = fmaf(qd, k1.z, out[6]);  out[7]  = fmaf(qd, k1.w, out[7]);
        out[8]  = fmaf(qd, k2.x, out[8]);  out[9]  = fmaf(qd, k2.y, out[9]);
        out[10] = fmaf(qd, k2.z, out[10]); out[11] = fmaf(qd, k2.w, out[11]);
        out[12] = fmaf(qd, k3.x, out[12]); out[13] = fmaf(qd, k3.y, out[13]);
        out[14] = fmaf(qd, k3.z, out[14]); out[15] = fmaf(qd, k3.w, out[15]);
    }

    const float inv = 1.f / (nrm + 1e-6f);
    const size_t gbase = ((size_t)b * SEQ + s0 + r) * DMODEL + h * HDIM + e0;
#pragma unroll
    for (int g4 = 0; g4 < 4; ++g4) {
        ushort4 H, L;
        const float v0 = out[g4*4+0] * inv;
        const float v1 = out[g4*4+1] * inv;
        const float v2 = out[g4*4+2] * inv;
        const float v3 = out[g4*4+3] * inv;
        H.x = f2bf(v0); L.x = f2bf(v0 - bf2f(H.x));
        H.y = f2bf(v1); L.y = f2bf(v1 - bf2f(H.y));
        H.z = f2bf(v2); L.z = f2bf(v2 - bf2f(H.z));
        H.w = f2bf(v3); L.w = f2bf(v3 - bf2f(H.w));
        *(ushort4*)&ah[gbase + g4 * 4] = H;
        *(ushort4*)&al[gbase + g4 * 4] = L;
    }
}

// ---------------------------------------------------------------------------
extern "C" void kernel_launch(void* const* d_in, const int* in_sizes, int n_in,
                              void* d_out, int out_size, void* d_ws, size_t ws_size,
                              hipStream_t stream)
{
    const float* x  = (const float*)d_in[0];
    const float* Wq = (const float*)d_in[1];
    const float* bq = (const float*)d_in[2];
    const float* Wk = (const float*)d_in[3];
    const float* bk = (const float*)d_in[4];
    const float* Wv = (const float*)d_in[5];
    const float* bv = (const float*)d_in[6];
    const float* Wo = (const float*)d_in[7];
    const float* bo = (const float*)d_in[8];

    // workspace layout (~153 MB):
    unsigned short* xh  = (unsigned short*)d_ws;                   // [16384][1024] bf16 hi (x, then att)
    unsigned short* xl  = xh + (size_t)NROWS * DMODEL;             // lo
    unsigned short* whi = xl + (size_t)NROWS * DMODEL;             // W hi block [4096][1024] rows [k|v|q|o]
    unsigned short* wlo = whi + 4u * M1;                           // W lo block
    float* buf0 = (float*)(wlo + 4u * M1);                         // k, then q (fp32)
    float* kv   = buf0 + (size_t)NROWS * DMODEL;                   // [NBH][64][64]
    float* ksum = kv + NBH * HDIM * HDIM;                          // [NBH][64]
    float* kvp  = ksum + NBH * HDIM;                               // [SCHUNK][NBH][64][64]
    float* ksp  = kvp + (size_t)SCHUNK * NBH * HDIM * HDIM;        // [SCHUNK][NBH][64]
    float* vbuf = (float*)d_out;                                   // v lives in d_out (dead before final GEMM)

    const int n4x = NROWS * DMODEL / 4;

    // convert weights + x to bf16 hi/lo
    split_w4<<<dim3(1024, 4), 256, 0, stream>>>(Wk, Wv, Wq, Wo, whi, wlo);
    split_pair<<<4096, 256, 0, stream>>>(x, xh, xl, n4x);
    // fused: k = elu(x@Wk^T + bk)+1 -> buf0 ; v = x@Wv^T + bv -> d_out
    gemm_pw<2><<<1024, 512, 0, stream>>>(xh, xl, whi, wlo, bk, bv, buf0, vbuf);
    // kv, ksum (deterministic split-K + reduce)
    kv_partial<<<dim3(NBH, SCHUNK), 512, 0, stream>>>(buf0, vbuf, kvp, ksp);
    kv_reduce<<<1024, 256, 0, stream>>>(kvp, ksp, kv, ksum);
    // q = elu(x@Wq^T + bq)+1   (overwrites k)
    gemm_pw<1><<<512, 512, 0, stream>>>(xh, xl, whi + 2u * M1, wlo + 2u * M1,
                                        bq, nullptr, buf0, nullptr);
    // att = (q@kv)/(q@ksum + 1e-6), fused bf16 hi/lo split (x split is dead)
    qkv_norm<<<dim3(SEQ / 64, NBATCH, NHEAD), 256, 0, stream>>>(buf0, kv, ksum, xh, xl);
    // out = att@Wo^T + bo  (overwrites v in d_out)
    gemm_pw<0><<<512, 512, 0, stream>>>(xh, xl, whi + 3u * M1, wlo + 3u * M1,
                                        bo, nullptr, (float*)d_out, nullptr);
}